// Round 7
// baseline (45.434 us; speedup 1.0000x reference)
//
#include <hip/hip_runtime.h>

#define GROUPS 64
#define DIMS 8
#define ACCW 10      // 8 sums + ssq + count
#define LSTRIDE 11   // LDS int stride (break pow2 bank pattern)
#define BPI 128      // blocks per image
#define BLK 256
#define NIMG 8
#define SLICES 8     // reducer blocks per image
#define XPS (BPI / SLICES)           // accum-blocks per reducer slice = 16
#define PWORDS (GROUPS * ACCW)       // 640 partial words per block
#define SCALE 262144.0f              // 2^18
#define INV_SCALE (1.0f / 262144.0f)

// ws layout (u64 words):
//   gacc2   [NIMG][PWORDS]               @ 0        (5120 w, memset)
//   ticket1 [NIMG]                       @ 5120     (memset)
//   ticket2 [1]                          @ 5128     (memset)
//   lossSlot[NIMG] (floats, 64B-aligned) @ 5136
//   part    [BPI*NIMG][PWORDS]           @ 5144     (5 MB, no zeroing needed)
#define OFF_T1   (NIMG * PWORDS)
#define OFF_T2   (OFF_T1 + NIMG)
#define OFF_LOSS (OFF_T2 + 8)
#define OFF_PART (OFF_LOSS + 8)

__global__ __launch_bounds__(BLK) void k_accum(const float* __restrict__ pred,
                                               const int* __restrict__ gt,
                                               unsigned long long* __restrict__ part,
                                               int N) {
    __shared__ int acc[4][GROUPS * LSTRIDE];
    const int tid = threadIdx.x;
    const int wave = tid >> 6;
    const int b = blockIdx.y;
    for (int i = tid; i < 4 * GROUPS * LSTRIDE; i += BLK) ((int*)acc)[i] = 0;
    __syncthreads();

    // ---- proven R0 inner loop, byte-identical ----
    const float4* pb = (const float4*)(pred + (size_t)b * N * DIMS);
    const int* gb = gt + (size_t)b * N;
    for (int idx = blockIdx.x * BLK + tid; idx < N; idx += BPI * BLK) {
        int g = gb[idx];
        float4 p0 = pb[2 * idx];
        float4 p1 = pb[2 * idx + 1];
        int* a = &acc[wave][g * LSTRIDE];
        atomicAdd(a + 0, __float2int_rn(p0.x * SCALE));
        atomicAdd(a + 1, __float2int_rn(p0.y * SCALE));
        atomicAdd(a + 2, __float2int_rn(p0.z * SCALE));
        atomicAdd(a + 3, __float2int_rn(p0.w * SCALE));
        atomicAdd(a + 4, __float2int_rn(p1.x * SCALE));
        atomicAdd(a + 5, __float2int_rn(p1.y * SCALE));
        atomicAdd(a + 6, __float2int_rn(p1.z * SCALE));
        atomicAdd(a + 7, __float2int_rn(p1.w * SCALE));
        float ssq = p0.x*p0.x + p0.y*p0.y + p0.z*p0.z + p0.w*p0.w
                  + p1.x*p1.x + p1.y*p1.y + p1.z*p1.z + p1.w*p1.w;
        atomicAdd(a + 8, __float2int_rn(ssq * SCALE));
        atomicAdd(a + 9, 1);
    }
    __syncthreads();

    // Atomic-free flush: each block owns a private contiguous 5 KB slice.
    // Plain coalesced u64 stores -- no same-address RMW serialization, no
    // end-of-kernel line-contention tail. Visibility to k_reduce comes from
    // the kernel-boundary L2 writeback the runtime performs between dispatches.
    unsigned long long* my = part + (size_t)(b * BPI + blockIdx.x) * PWORDS;
    for (int i = tid; i < PWORDS; i += BLK) {
        int g = i / ACCW, k = i % ACCW;
        long long v = (long long)acc[0][g * LSTRIDE + k]
                    + (long long)acc[1][g * LSTRIDE + k]
                    + (long long)acc[2][g * LSTRIDE + k]
                    + (long long)acc[3][g * LSTRIDE + k];
        my[i] = (unsigned long long)v;
    }
}

__global__ __launch_bounds__(PWORDS) void k_reduce(unsigned long long* __restrict__ ws,
                                                   float* __restrict__ out) {
    __shared__ float sm[GROUPS][DIMS + 1];
    __shared__ int isLast;
    const int tid = threadIdx.x;          // 0..639, one partial word each
    const int b = blockIdx.y;             // image
    const int s = blockIdx.x;             // slice of 16 accum-blocks

    unsigned long long* gacc2 = ws;
    unsigned long long* ticket1 = ws + OFF_T1;
    unsigned long long* ticket2 = ws + OFF_T2;
    float* lossSlot = (float*)(ws + OFF_LOSS);
    const unsigned long long* part = ws + OFF_PART;

    // Sum 16 block-partials for word tid (coalesced: 5 KB contiguous per x).
    long long sum = 0;
    const unsigned long long* p0 = part + ((size_t)(b * BPI + s * XPS)) * PWORDS + tid;
    #pragma unroll
    for (int x = 0; x < XPS; ++x) sum += (long long)p0[(size_t)x * PWORDS];
    atomicAdd(&gacc2[b * PWORDS + tid], (unsigned long long)sum);

    // barrier drains vmcnt per wave -> this block's adds are at the coherent
    // point before the ticket RMW (pattern verified absmax=0.0 in R2-R5).
    __syncthreads();
    if (tid == 0) {
        unsigned long long t = __hip_atomic_fetch_add(&ticket1[b], 1ull, __ATOMIC_RELAXED,
                                                      __HIP_MEMORY_SCOPE_AGENT);
        isLast = (t == (unsigned long long)SLICES - 1ull) ? 1 : 0;
    }
    __syncthreads();
    if (!isLast) return;

    // ---------- per-image finisher: wave 0 of the last slice-block ----------
    if (tid < GROUPS) {
        const int g = tid;
        long long ga[ACCW];
        for (int k = 0; k < ACCW; ++k)
            ga[k] = (long long)__hip_atomic_load(&gacc2[b * PWORDS + g * ACCW + k],
                                                 __ATOMIC_RELAXED, __HIP_MEMORY_SCOPE_AGENT);
        float c = (float)ga[9];
        float ssq = (float)ga[8] * INV_SCALE;
        float safe = fmaxf(c, 1.f);
        float m[DIMS];
        float msq = 0.f;
        for (int d = 0; d < DIMS; ++d) {
            m[d] = ((float)ga[d] * INV_SCALE) / safe;
            sm[g][d] = m[d];
            msq += m[d] * m[d];
        }
        bool present = c > 0.f;
        sm[g][DIMS] = present ? 1.f : 0.f;

        float sumsq = ssq - c * msq;
        float pull_g = present ? sumsq / (safe * (float)DIMS) : 0.f;

        unsigned long long mask = __ballot(present);
        float num = (float)__popcll(mask);

        float pull = pull_g;
        for (int off = 32; off; off >>= 1) pull += __shfl_xor(pull, off);

        // same-wave LDS write->read, in-order DS pipe (verified R2-R5)
        float pg = 0.f;
        if (present) {
            for (int j = 0; j < GROUPS; ++j) {
                float pm = sm[j][DIMS];
                float d2 = 0.f;
                for (int d = 0; d < DIMS; ++d) {
                    float t2 = m[d] - sm[j][d];
                    d2 += t2 * t2;
                }
                pg += pm * expf(-d2);
            }
        }
        for (int off = 32; off; off >>= 1) pg += __shfl_xor(pg, off);

        if (g == 0) {
            float push = (pg - num) / ((num - 1.f) * num + 1e-6f) * 0.5f;
            float loss_b = push + pull / (num + 1e-6f);
            __hip_atomic_store(&lossSlot[b], loss_b, __ATOMIC_RELAXED,
                               __HIP_MEMORY_SCOPE_AGENT);
            // reading t2 forces s_waitcnt vmcnt(0), which also completes the
            // lossSlot store above (same wave, in-order vmcnt drain).
            unsigned long long t2 = __hip_atomic_fetch_add(ticket2, 1ull, __ATOMIC_RELAXED,
                                                           __HIP_MEMORY_SCOPE_AGENT);
            if (t2 == (unsigned long long)NIMG - 1ull) {
                float ssum = 0.f;
                for (int i = 0; i < NIMG; ++i)
                    ssum += __hip_atomic_load(&lossSlot[i], __ATOMIC_RELAXED,
                                              __HIP_MEMORY_SCOPE_AGENT);
                out[0] = ssum * (1.f / (float)NIMG);
            }
        }
    }
}

extern "C" void kernel_launch(void* const* d_in, const int* in_sizes, int n_in,
                              void* d_out, int out_size, void* d_ws, size_t ws_size,
                              hipStream_t stream) {
    const float* pred = (const float*)d_in[0];
    const int* gt = (const int*)d_in[1];
    const int N = in_sizes[1] / NIMG;   // 500000

    unsigned long long* ws = (unsigned long long*)d_ws;
    unsigned long long* part = ws + OFF_PART;

    // zero gacc2 + tickets only (41 KB); part[] is overwritten, no zeroing
    hipMemsetAsync(d_ws, 0, (OFF_T2 + 1) * sizeof(unsigned long long), stream);

    dim3 grid(BPI, NIMG);
    k_accum<<<grid, BLK, 0, stream>>>(pred, gt, part, N);
    dim3 rgrid(SLICES, NIMG);
    k_reduce<<<rgrid, PWORDS, 0, stream>>>(ws, (float*)d_out);
}